// Round 3
// baseline (698.415 us; speedup 1.0000x reference)
//
#include <hip/hip_runtime.h>
#include <hip/hip_bf16.h>

// Problem constants
#define B_  4096
#define T_  80
#define E_  100
#define U_  64
#define G_  256    // 4*U
#define V_  10000

#define ROWS 8     // batch rows per block -> 512 blocks = 2 blocks/CU
#define S_H  72    // hbuf row stride (bf16 elems), 144B rows (16B aligned)
#define ZS   72    // zw row stride (fp32 words): 8*row spacing -> 2-way max (free)

typedef __attribute__((ext_vector_type(8))) __bf16 bf16x8;
typedef __attribute__((ext_vector_type(4))) float  floatx4;

__device__ __forceinline__ float sigmoidf_(float x) {
    return __fdividef(1.f, 1.f + __expf(-x));
}

__device__ __forceinline__ float tanhf_(float x) {
    // 1 - 2/(e^{2x}+1): x->+inf: 1-0=1; x->-inf: 1-2=-1; no NaN, no abs/copysign
    return 1.f - __fdividef(2.f, __expf(2.f * x) + 1.f);
}

// ---------------------------------------------------------------------------
// Kernel A: embk[v][g] = b1[g] + emb[v] . k1[:,g]
// 64 vocab rows/block. K chunked {32,32,32,4} so only 32 kcol regs live (no
// spill); 16 row-accumulators for fma ILP; float4 broadcast LDS reads.
// ---------------------------------------------------------------------------
__global__ __launch_bounds__(256) void embk_kernel(const float* __restrict__ emb,
                                                   const float* __restrict__ k1,
                                                   const float* __restrict__ b1,
                                                   float* __restrict__ embk) {
    __shared__ float eLDS[64 * E_];          // 25.6 KB
    const int g  = threadIdx.x;              // gate column 0..255
    const int v0 = blockIdx.x * 64;
    const int nrows = min(64, V_ - v0);

    for (int i = g; i < nrows * E_; i += 256) eLDS[i] = emb[(long)v0 * E_ + i];
    const float bias = b1[g];
    __syncthreads();

    for (int rb = 0; rb < 64; rb += 16) {
        if (rb >= nrows) break;
        float acc[16];
#pragma unroll
        for (int r = 0; r < 16; ++r) acc[r] = bias;

#pragma unroll
        for (int kc = 0; kc < 4; ++kc) {
            constexpr int K0[4] = {0, 32, 64, 96};
            constexpr int KN[4] = {32, 32, 32, 4};
            const int k0 = K0[kc], kn = KN[kc];
            float kcol[32];
#pragma unroll
            for (int e = 0; e < 32; ++e)
                if (e < kn) kcol[e] = k1[(k0 + e) * G_ + g];
#pragma unroll
            for (int r = 0; r < 16; ++r) {
                const float* er = eLDS + (rb + r) * E_ + k0;
#pragma unroll
                for (int e4 = 0; e4 < 8; ++e4) {
                    if (e4 * 4 >= kn) break;
                    float4 ev = *(const float4*)(er + 4 * e4);
                    acc[r] = fmaf(ev.x, kcol[4 * e4 + 0], acc[r]);
                    acc[r] = fmaf(ev.y, kcol[4 * e4 + 1], acc[r]);
                    acc[r] = fmaf(ev.z, kcol[4 * e4 + 2], acc[r]);
                    acc[r] = fmaf(ev.w, kcol[4 * e4 + 3], acc[r]);
                }
            }
        }
#pragma unroll
        for (int r = 0; r < 16; ++r)
            if (rb + r < nrows) embk[(long)(v0 + rb + r) * G_ + g] = acc[r];
    }
}

// ---------------------------------------------------------------------------
// Kernel B: recurrence. 512 blocks x 256 threads, 8 batch rows per block
// (2 blocks/CU). Wave w owns units [w*16, w*16+16). Per step:
//   MFMA (M=16 tile, rows 8..15 = zero padding) -> z for valid rows via
//   wave-private LDS (intra-wave, NO barrier) -> 2 live cells/lane gate math
//   -> h (bf16) to double-buffered LDS -> ONE __syncthreads.
// ---------------------------------------------------------------------------
__global__ __launch_bounds__(256, 2) void lstm_kernel(const int*   __restrict__ tokens,
                                                      const float* __restrict__ embk,
                                                      const float* __restrict__ r1,
                                                      const float* __restrict__ Wd,
                                                      const float* __restrict__ bd,
                                                      float* __restrict__ out) {
    __shared__ int    tokLDS[ROWS * T_];        // 2.56 KB
    __shared__ __bf16 hbuf[2][16 * S_H];        // 4.6 KB (rows 8..15 stay zero)
    __shared__ float  zw[4][ROWS * ZS];         // 9.2 KB, wave-private z scratch

    const int tid  = threadIdx.x;
    const int lane = tid & 63;
    const int w    = tid >> 6;               // wave id: owns units [w*16, w*16+16)
    const int n    = lane & 15;
    const int kg   = lane >> 4;              // 0..3
    const int bb   = blockIdx.x * ROWS;
    const int cb   = w * 16 + n;             // global unit column for MFMA B/C

    for (int i = tid; i < ROWS * T_; i += 256) tokLDS[i] = tokens[bb * T_ + i];
    for (int i = tid; i < 2 * 16 * S_H; i += 256) hbuf[0][i] = (__bf16)0.f;  // flat zero both buffers

    // r1 B-fragments (held in VGPRs whole loop): B[k][col], col = j*64 + cb,
    // k = kc*32 + kg*8 + jj
    bf16x8 bfr[4][2];
#pragma unroll
    for (int j = 0; j < 4; ++j)
#pragma unroll
        for (int kc = 0; kc < 2; ++kc) {
            bf16x8 s;
#pragma unroll
            for (int jj = 0; jj < 8; ++jj)
                s[jj] = (__bf16)r1[(kc * 32 + kg * 8 + jj) * G_ + j * 64 + cb];
            bfr[j][kc] = s;
        }

    // gate-phase cells (intra-wave balanced): (b = kg + 4*ci, u = cb), ci=0,1
    float c[2] = {0.f, 0.f};
    float hfin[2] = {0.f, 0.f};

    __syncthreads();                         // tokens + zeroed hbuf visible

    // xk prefetch for t=0 (C-layout: xk[j][r] for row kg*4+r); only rows 0..7 live
    float xk[4][4];
#pragma unroll
    for (int j = 0; j < 4; ++j)
#pragma unroll
        for (int r = 0; r < 4; ++r) xk[j][r] = 0.f;
    if (kg < 2) {
        int trow[4];
#pragma unroll
        for (int r = 0; r < 4; ++r) trow[r] = tokLDS[(kg * 4 + r) * T_ + 0];
#pragma unroll
        for (int r = 0; r < 4; ++r) {
            const float* rbase = embk + (long)trow[r] * G_;
#pragma unroll
            for (int j = 0; j < 4; ++j) xk[j][r] = rbase[j * 64 + cb];
        }
    }

    float* zme = zw[w];

    for (int t = 0; t < T_; ++t) {
        // A-fragments of h_{t-1}: A[m][k], m = n (batch row; 8..15 are zeros)
        const __bf16* hb = hbuf[(t + 1) & 1];
        bf16x8 a0 = *(const bf16x8*)(hb + n * S_H + kg * 8);
        bf16x8 a1 = *(const bf16x8*)(hb + n * S_H + 32 + kg * 8);

        floatx4 acc[4];
#pragma unroll
        for (int j = 0; j < 4; ++j) {
            floatx4 a = {xk[j][0], xk[j][1], xk[j][2], xk[j][3]};
            a = __builtin_amdgcn_mfma_f32_16x16x32_bf16(a0, bfr[j][0], a, 0, 0, 0);
            a = __builtin_amdgcn_mfma_f32_16x16x32_bf16(a1, bfr[j][1], a, 0, 0, 0);
            acc[j] = a;
        }

        // prefetch next step's xk
        if (t + 1 < T_ && kg < 2) {
            int trow[4];
#pragma unroll
            for (int r = 0; r < 4; ++r) trow[r] = tokLDS[(kg * 4 + r) * T_ + t + 1];
#pragma unroll
            for (int r = 0; r < 4; ++r) {
                const float* rbase = embk + (long)trow[r] * G_;
#pragma unroll
                for (int j = 0; j < 4; ++j) xk[j][r] = rbase[j * 64 + cb];
            }
        }

        // z for valid rows -> wave-private LDS (intra-wave; lgkmcnt only)
        if (kg < 2) {
#pragma unroll
            for (int j = 0; j < 4; ++j)
#pragma unroll
                for (int r = 0; r < 4; ++r)
                    zme[(kg * 4 + r) * ZS + j * 16 + n] = acc[j][r];
        }
        __builtin_amdgcn_wave_barrier();     // scheduling fence (no-op instr)

        // gate math: 2 live cells/lane (b = kg + 4*ci, unit = cb)
        __bf16* hw = hbuf[t & 1];
#pragma unroll
        for (int ci = 0; ci < 2; ++ci) {
            const int b = kg + 4 * ci;
            const float* zb = zme + b * ZS;
            float zi = zb[0 * 16 + n];
            float zf = zb[1 * 16 + n];
            float zg = zb[2 * 16 + n];
            float zo = zb[3 * 16 + n];
            float cn = sigmoidf_(zf) * c[ci] + sigmoidf_(zi) * tanhf_(zg);
            float hn = sigmoidf_(zo) * tanhf_(cn);
            c[ci] = cn;
            hfin[ci] = hn;
            hw[b * S_H + cb] = (__bf16)hn;
        }

        __syncthreads();                     // h_t visible; also WAR on hbuf
    }

    // out[b] = sigmoid(h_final[b] . Wd + bd); h_79 in hbuf[1] rows 0..7
    if (tid < ROWS) {
        const __bf16* hb = hbuf[1] + tid * S_H;
        float s = bd[0];
#pragma unroll
        for (int u = 0; u < U_; ++u) s = fmaf((float)hb[u], Wd[u], s);
        out[bb + tid] = sigmoidf_(s);
    }
    (void)hfin;
}

// ---------------------------------------------------------------------------
extern "C" void kernel_launch(void* const* d_in, const int* in_sizes, int n_in,
                              void* d_out, int out_size, void* d_ws, size_t ws_size,
                              hipStream_t stream) {
    const int*   tokens = (const int*)  d_in[0];
    const float* emb    = (const float*)d_in[1];
    // d_in[2..4] = k0, r0, b0 : dead in the reference (cell0 state unused)
    const float* k1     = (const float*)d_in[5];
    const float* r1     = (const float*)d_in[6];
    const float* b1     = (const float*)d_in[7];
    const float* Wd     = (const float*)d_in[8];
    const float* bd     = (const float*)d_in[9];
    float*       out    = (float*)d_out;

    float* embk = (float*)d_ws;              // V_*G_ floats = 10.24 MB

    embk_kernel<<<(V_ + 63) / 64, 256, 0, stream>>>(emb, k1, b1, embk);
    lstm_kernel<<<B_ / ROWS, 256, 0, stream>>>(tokens, embk, r1, Wd, bd, out);
}

// Round 4
// 223.656 us; speedup vs baseline: 3.1227x; 3.1227x over previous
//
#include <hip/hip_runtime.h>
#include <hip/hip_bf16.h>

// Problem constants
#define B_  4096
#define T_  80
#define E_  100
#define U_  64
#define G_  256    // 4*U
#define V_  10000

#define ROWS 8     // batch rows per lstm block -> 512 blocks = 2 blocks/CU
#define S_H  72    // hbuf row stride (bf16 elems), 144B rows (16B aligned)
#define AS   136   // embk A-tile LDS stride (bf16): 272B rows, 16B aligned

typedef __attribute__((ext_vector_type(8))) __bf16 bf16x8;
typedef __attribute__((ext_vector_type(4))) float  floatx4;

__device__ __forceinline__ float sigmoidf_(float x) {
    return __fdividef(1.f, 1.f + __expf(-x));
}

__device__ __forceinline__ float tanhf_(float x) {
    // 1 - 2/(e^{2x}+1): monotone, saturates correctly, no NaN
    return 1.f - __fdividef(2.f, __expf(2.f * x) + 1.f);
}

// ---------------------------------------------------------------------------
// Kernel A (MFMA): embk[v][g] = b1[g] + emb[v] . k1[:,g]
// M=10000, K=100 (zero-padded to 128), N=256. 64 vocab rows per block.
// A (emb rows, bf16) staged in LDS; B-fragments (k1, bf16) in VGPRs;
// bias in the MFMA C-init; fp32 accumulate. No private arrays that can spill.
// ---------------------------------------------------------------------------
__global__ __launch_bounds__(256) void embk_kernel(const float* __restrict__ emb,
                                                   const float* __restrict__ k1,
                                                   const float* __restrict__ b1,
                                                   float* __restrict__ embk) {
    __shared__ __bf16 aLDS[64 * AS];         // 17.4 KB

    const int tid  = threadIdx.x;
    const int lane = tid & 63;
    const int w    = tid >> 6;               // wave: owns cols [w*64, w*64+64)
    const int n    = lane & 15;
    const int kg   = lane >> 4;
    const int v0   = blockIdx.x * 64;
    const int nrows = min(64, V_ - v0);

    // zero the K-pad region e in [100,128) (cols 128..135 never read)
    for (int i = tid; i < 64 * 28; i += 256) {
        int r = i / 28, e = 100 + (i - r * 28);
        aLDS[r * AS + e] = (__bf16)0.f;
    }
    // stage emb rows (coalesced fp32 reads -> bf16); no overlap with pad region
    for (int i = tid; i < nrows * E_; i += 256) {
        int r = i / E_, e = i - r * E_;
        aLDS[r * AS + e] = (__bf16)emb[(long)v0 * E_ + i];
    }

    // B-fragments for this wave's 4 col-tiles, 4 K-chunks (64 VGPRs total)
    // B[k][col]: col = w*64 + ct*16 + n, k = kc*32 + kg*8 + jj (0 for k>=100)
    bf16x8 bfr[4][4];
#pragma unroll
    for (int ct = 0; ct < 4; ++ct)
#pragma unroll
        for (int kc = 0; kc < 4; ++kc) {
            bf16x8 s;
#pragma unroll
            for (int jj = 0; jj < 8; ++jj) {
                int k = kc * 32 + kg * 8 + jj;
                s[jj] = (k < E_) ? (__bf16)k1[k * G_ + w * 64 + ct * 16 + n]
                                 : (__bf16)0.f;
            }
            bfr[ct][kc] = s;
        }

    float bv0 = b1[w * 64 +  0 + n];
    float bv1 = b1[w * 64 + 16 + n];
    float bv2 = b1[w * 64 + 32 + n];
    float bv3 = b1[w * 64 + 48 + n];

    __syncthreads();

#pragma unroll
    for (int mt = 0; mt < 4; ++mt) {
        // A-frag: A[m][k], m = mt*16+n, k = kc*32 + kg*8 + jj
        const __bf16* ab = aLDS + (mt * 16 + n) * AS + kg * 8;
        bf16x8 a0 = *(const bf16x8*)(ab + 0 * 32);
        bf16x8 a1 = *(const bf16x8*)(ab + 1 * 32);
        bf16x8 a2 = *(const bf16x8*)(ab + 2 * 32);
        bf16x8 a3 = *(const bf16x8*)(ab + 3 * 32);
#pragma unroll
        for (int ct = 0; ct < 4; ++ct) {
            float bv = (ct == 0) ? bv0 : (ct == 1) ? bv1 : (ct == 2) ? bv2 : bv3;
            floatx4 acc = {bv, bv, bv, bv};
            acc = __builtin_amdgcn_mfma_f32_16x16x32_bf16(a0, bfr[ct][0], acc, 0, 0, 0);
            acc = __builtin_amdgcn_mfma_f32_16x16x32_bf16(a1, bfr[ct][1], acc, 0, 0, 0);
            acc = __builtin_amdgcn_mfma_f32_16x16x32_bf16(a2, bfr[ct][2], acc, 0, 0, 0);
            acc = __builtin_amdgcn_mfma_f32_16x16x32_bf16(a3, bfr[ct][3], acc, 0, 0, 0);
            // C/D: row = kg*4 + r, col = n (within tile)
#pragma unroll
            for (int r = 0; r < 4; ++r) {
                int v = v0 + mt * 16 + kg * 4 + r;
                if (v < V_) embk[(long)v * G_ + w * 64 + ct * 16 + n] = acc[r];
            }
        }
    }
}

// ---------------------------------------------------------------------------
// Kernel B: recurrence (R1 register-z structure, ROWS=8 -> 2 blocks/CU).
// Block = 8 batch rows, 4 waves; wave w owns units [w*16, w*16+16) =
// col-tiles {w, w+4, w+8, w+12} (its units' i,f,g,o columns) -> gate z
// stays in MFMA accumulators, gate math fully in registers. M-tile rows
// 8..15 are zero padding. h double-buffered in LDS; ONE barrier per step.
// ---------------------------------------------------------------------------
__global__ __launch_bounds__(256) void lstm_kernel(const int*   __restrict__ tokens,
                                                   const float* __restrict__ embk,
                                                   const float* __restrict__ r1,
                                                   const float* __restrict__ Wd,
                                                   const float* __restrict__ bd,
                                                   float* __restrict__ out) {
    __shared__ int    tokLDS[ROWS * T_];     // 2.56 KB
    __shared__ __bf16 hbuf[2][16 * S_H];     // 4.6 KB (rows 8..15 stay zero)

    const int tid  = threadIdx.x;
    const int lane = tid & 63;
    const int w    = tid >> 6;               // unit-chunk 0..3
    const int n    = lane & 15;
    const int kg   = lane >> 4;
    const int bb   = blockIdx.x * ROWS;
    const int cb   = w * 16 + n;             // this lane's unit column u

    for (int i = tid; i < ROWS * T_; i += 256) tokLDS[i] = tokens[bb * T_ + i];
    for (int i = tid; i < 2 * 16 * S_H; i += 256) (&hbuf[0][0])[i] = (__bf16)0.f;

    // r1 B-fragments (VGPR-resident whole loop): col = j*64 + cb,
    // k = kc*32 + kg*8 + jj
    bf16x8 bfr[4][2];
#pragma unroll
    for (int j = 0; j < 4; ++j)
#pragma unroll
        for (int kc = 0; kc < 2; ++kc) {
            bf16x8 s;
#pragma unroll
            for (int jj = 0; jj < 8; ++jj)
                s[jj] = (__bf16)r1[(kc * 32 + kg * 8 + jj) * G_ + j * 64 + cb];
            bfr[j][kc] = s;
        }

    // cell state: (b = kg*4 + r, u = cb); rows >= 8 are padding (stay 0)
    float c[4] = {0.f, 0.f, 0.f, 0.f};
    float h[4] = {0.f, 0.f, 0.f, 0.f};

    __syncthreads();                         // tokens + zeroed hbuf visible

    // xk prefetch for t=0 (C-layout); only rows 0..7 are live
    float xk[4][4];
#pragma unroll
    for (int j = 0; j < 4; ++j)
#pragma unroll
        for (int r = 0; r < 4; ++r) xk[j][r] = 0.f;
    if (kg < 2) {
#pragma unroll
        for (int r = 0; r < 4; ++r) {
            const float* rbase = embk + (long)tokLDS[(kg * 4 + r) * T_ + 0] * G_;
#pragma unroll
            for (int j = 0; j < 4; ++j) xk[j][r] = rbase[j * 64 + cb];
        }
    }

    for (int t = 0; t < T_; ++t) {
        // A-fragments of h_{t-1}: A[m][k], m = n (rows 8..15 zeros)
        const __bf16* hb = hbuf[(t + 1) & 1];
        bf16x8 a0 = *(const bf16x8*)(hb + n * S_H + kg * 8);
        bf16x8 a1 = *(const bf16x8*)(hb + n * S_H + 32 + kg * 8);

        // z = xk + h @ r1, per gate j, entirely in registers
        floatx4 acc[4];
#pragma unroll
        for (int j = 0; j < 4; ++j) {
            floatx4 a = {xk[j][0], xk[j][1], xk[j][2], xk[j][3]};
            a = __builtin_amdgcn_mfma_f32_16x16x32_bf16(a0, bfr[j][0], a, 0, 0, 0);
            a = __builtin_amdgcn_mfma_f32_16x16x32_bf16(a1, bfr[j][1], a, 0, 0, 0);
            acc[j] = a;
        }

        // prefetch next step's xk (hidden under gate math + barrier)
        if (t + 1 < T_ && kg < 2) {
#pragma unroll
            for (int r = 0; r < 4; ++r) {
                const float* rbase = embk + (long)tokLDS[(kg * 4 + r) * T_ + t + 1] * G_;
#pragma unroll
                for (int j = 0; j < 4; ++j) xk[j][r] = rbase[j * 64 + cb];
            }
        }

        // gates: rows b = kg*4 + r; padding rows compute zeros harmlessly
        __bf16* hw = hbuf[t & 1];
#pragma unroll
        for (int r = 0; r < 4; ++r) {
            float zi = acc[0][r], zf = acc[1][r], zg = acc[2][r], zo = acc[3][r];
            float cn = sigmoidf_(zf) * c[r] + sigmoidf_(zi) * tanhf_(zg);
            float hn = sigmoidf_(zo) * tanhf_(cn);
            c[r] = cn;
            h[r] = hn;
            hw[(kg * 4 + r) * S_H + cb] = (__bf16)hn;
        }

        __syncthreads();                     // h_t visible; WAR on hbuf
    }

    // out[b] = sigmoid(h_final[b] . Wd + bd); h_79 in hbuf[1] rows 0..7
    if (tid < ROWS) {
        const __bf16* hb = hbuf[1] + tid * S_H;
        float s = bd[0];
#pragma unroll
        for (int u = 0; u < U_; ++u) s = fmaf((float)hb[u], Wd[u], s);
        out[bb + tid] = sigmoidf_(s);
    }
    (void)h;
}

// ---------------------------------------------------------------------------
extern "C" void kernel_launch(void* const* d_in, const int* in_sizes, int n_in,
                              void* d_out, int out_size, void* d_ws, size_t ws_size,
                              hipStream_t stream) {
    const int*   tokens = (const int*)  d_in[0];
    const float* emb    = (const float*)d_in[1];
    // d_in[2..4] = k0, r0, b0 : dead in the reference (cell0 state unused)
    const float* k1     = (const float*)d_in[5];
    const float* r1     = (const float*)d_in[6];
    const float* b1     = (const float*)d_in[7];
    const float* Wd     = (const float*)d_in[8];
    const float* bd     = (const float*)d_in[9];
    float*       out    = (float*)d_out;

    float* embk = (float*)d_ws;              // V_*G_ floats = 10.24 MB

    embk_kernel<<<(V_ + 63) / 64, 256, 0, stream>>>(emb, k1, b1, embk);
    lstm_kernel<<<B_ / ROWS, 256, 0, stream>>>(tokens, embk, r1, Wd, bd, out);
}

// Round 5
// 161.984 us; speedup vs baseline: 4.3116x; 1.3807x over previous
//
#include <hip/hip_runtime.h>
#include <hip/hip_bf16.h>

// Problem constants
#define B_  4096
#define T_  80
#define E_  100
#define U_  64
#define G_  256    // 4*U
#define V_  10000

#define S_H  72    // hbuf row stride (bf16 elems), 144B rows (16B aligned)
#define AS   136   // embk A-tile LDS stride (bf16): 272B rows, 16B aligned, %8==0

typedef __attribute__((ext_vector_type(8))) __bf16 bf16x8;
typedef __attribute__((ext_vector_type(4))) __bf16 bf16x4;
typedef __attribute__((ext_vector_type(4))) float  floatx4;

__device__ __forceinline__ float sigmoidf_(float x) {
    return __fdividef(1.f, 1.f + __expf(-x));
}

__device__ __forceinline__ float tanhf_(float x) {
    // 1 - 2/(e^{2x}+1): monotone, saturates correctly, no NaN
    return 1.f - __fdividef(2.f, __expf(2.f * x) + 1.f);
}

// one LSTM cell update in registers; writes h (bf16) to LDS
__device__ __forceinline__ void cell_update_(float zi, float zf, float zg, float zo,
                                             float& c, __bf16* hdst) {
    float cn = sigmoidf_(zf) * c + sigmoidf_(zi) * tanhf_(zg);
    float hn = sigmoidf_(zo) * tanhf_(cn);
    c = cn;
    *hdst = (__bf16)hn;
}

// ---------------------------------------------------------------------------
// Kernel A (MFMA): embk[v][g] = b1[g] + emb[v] . k1[:,g]
// Grid = 157 vocab-tiles x 2 N-halves = 314 blocks. Per block: 64 rows x 128
// cols. A (bf16) in LDS via float4->bf16x4; B-frags = 8 bf16x8 = 64 VGPRs.
// K zero-padded 100->128. Bias in C-init, fp32 accum. No spillable arrays.
// ---------------------------------------------------------------------------
__global__ __launch_bounds__(256) void embk_kernel(const float* __restrict__ emb,
                                                   const float* __restrict__ k1,
                                                   const float* __restrict__ b1,
                                                   float* __restrict__ embk) {
    __shared__ __bf16 aLDS[64 * AS];         // 17.4 KB

    const int tid  = threadIdx.x;
    const int lane = tid & 63;
    const int w    = tid >> 6;               // wave: owns cols n0 + [w*32, w*32+32)
    const int n    = lane & 15;
    const int kg   = lane >> 4;
    const int v0   = (blockIdx.x >> 1) * 64;
    const int n0   = (blockIdx.x & 1) * 128;
    const int nrows = min(64, V_ - v0);

    // zero all of aLDS (covers the K-pad region [100,136))
    for (int i = tid; i < 64 * AS / 8; i += 256) {
        bf16x8 z;
#pragma unroll
        for (int jj = 0; jj < 8; ++jj) z[jj] = (__bf16)0.f;
        *(bf16x8*)(aLDS + i * 8) = z;
    }

    // B-fragments (independent of LDS; overlaps barriers): col = n0+w*32+ct*16+n
    bf16x8 bfr[2][4];
#pragma unroll
    for (int ct = 0; ct < 2; ++ct)
#pragma unroll
        for (int kc = 0; kc < 4; ++kc) {
            bf16x8 s;
#pragma unroll
            for (int jj = 0; jj < 8; ++jj) {
                int k = kc * 32 + kg * 8 + jj;
                s[jj] = (k < E_) ? (__bf16)k1[k * G_ + n0 + w * 32 + ct * 16 + n]
                                 : (__bf16)0.f;
            }
            bfr[ct][kc] = s;
        }
    const float bv0 = b1[n0 + w * 32 + n];
    const float bv1 = b1[n0 + w * 32 + 16 + n];

    __syncthreads();                         // zeroing done

    // stage emb rows: 25 float4 per row, bf16x4 LDS writes (8B aligned)
    for (int i = tid; i < nrows * 25; i += 256) {
        int r = i / 25, q = i - r * 25;
        float4 ev = *(const float4*)(emb + (long)(v0 + r) * E_ + q * 4);
        bf16x4 bv; bv[0] = (__bf16)ev.x; bv[1] = (__bf16)ev.y;
                   bv[2] = (__bf16)ev.z; bv[3] = (__bf16)ev.w;
        *(bf16x4*)(aLDS + r * AS + q * 4) = bv;
    }
    __syncthreads();

#pragma unroll
    for (int mt = 0; mt < 4; ++mt) {
        const __bf16* ab = aLDS + (mt * 16 + n) * AS + kg * 8;
        bf16x8 a0 = *(const bf16x8*)(ab + 0);
        bf16x8 a1 = *(const bf16x8*)(ab + 32);
        bf16x8 a2 = *(const bf16x8*)(ab + 64);
        bf16x8 a3 = *(const bf16x8*)(ab + 96);
#pragma unroll
        for (int ct = 0; ct < 2; ++ct) {
            float bv = ct ? bv1 : bv0;
            floatx4 acc = {bv, bv, bv, bv};
            acc = __builtin_amdgcn_mfma_f32_16x16x32_bf16(a0, bfr[ct][0], acc, 0, 0, 0);
            acc = __builtin_amdgcn_mfma_f32_16x16x32_bf16(a1, bfr[ct][1], acc, 0, 0, 0);
            acc = __builtin_amdgcn_mfma_f32_16x16x32_bf16(a2, bfr[ct][2], acc, 0, 0, 0);
            acc = __builtin_amdgcn_mfma_f32_16x16x32_bf16(a3, bfr[ct][3], acc, 0, 0, 0);
            // C/D: row = kg*4 + r, col = n (within tile)
#pragma unroll
            for (int r = 0; r < 4; ++r) {
                int v = v0 + mt * 16 + kg * 4 + r;
                if (v < V_) embk[(long)v * G_ + n0 + w * 32 + ct * 16 + n] = acc[r];
            }
        }
    }
}

// ---------------------------------------------------------------------------
// Kernel B: recurrence. 256 blocks x 512 threads (8 waves = 2/SIMD).
// Block = 16 batch rows. Wave (w4 = w&3, role = w>>2): w4 picks the unit
// chunk [w4*16, w4*16+16) (col-tiles {w4, w4+4, w4+8, w4+12} = that chunk's
// i,f,g,o columns); waves w4 and w4+4 compute IDENTICAL MFMAs (redundant,
// cheap) and split the 16 accumulator rows: role 0 -> regs {0,1}, role 1 ->
// regs {2,3}. Every lane does exactly 2 live cells of gate math. xk added
// post-MFMA for consumed rows only (8 gathers/lane/step). h double-buffered
// in LDS; ONE barrier per step.
// ---------------------------------------------------------------------------
__global__ __launch_bounds__(512) void lstm_kernel(const int*   __restrict__ tokens,
                                                   const float* __restrict__ embk,
                                                   const float* __restrict__ r1,
                                                   const float* __restrict__ Wd,
                                                   const float* __restrict__ bd,
                                                   float* __restrict__ out) {
    __shared__ int    tokLDS[16 * T_];       // 5.12 KB
    __shared__ __bf16 hbuf[2][16 * S_H];     // 4.6 KB

    const int tid  = threadIdx.x;
    const int lane = tid & 63;
    const int w    = tid >> 6;               // 0..7
    const int w4   = w & 3;                  // unit chunk
    const int role = w >> 2;                 // 0: regs {0,1}, 1: regs {2,3}
    const int n    = lane & 15;
    const int kg   = lane >> 4;
    const int bb   = blockIdx.x * 16;
    const int cb   = w4 * 16 + n;            // this lane's unit column u
    const int b0   = kg * 4 + role * 2;      // first consumed row
    const int b1   = b0 + 1;                 // second consumed row

    for (int i = tid; i < 16 * T_; i += 512) tokLDS[i] = tokens[bb * T_ + i];
    for (int i = tid; i < 2 * 16 * S_H; i += 512) (&hbuf[0][0])[i] = (__bf16)0.f;

    // r1 B-fragments (VGPR-resident): col = j*64 + cb, k = kc*32 + kg*8 + jj
    bf16x8 bfr[4][2];
#pragma unroll
    for (int j = 0; j < 4; ++j)
#pragma unroll
        for (int kc = 0; kc < 2; ++kc) {
            bf16x8 s;
#pragma unroll
            for (int jj = 0; jj < 8; ++jj)
                s[jj] = (__bf16)r1[(kc * 32 + kg * 8 + jj) * G_ + j * 64 + cb];
            bfr[j][kc] = s;
        }

    float c0 = 0.f, c1 = 0.f;                // cell state for rows b0, b1 (unit cb)

    __syncthreads();                         // tokens + zeroed hbuf visible

    // xk for t=0: xkc[j][{0,1}] = embk[tok[b0/b1]][j*64+cb]
    float xkc[4][2];
    {
        const float* pa = embk + (long)tokLDS[b0 * T_ + 0] * G_;
        const float* pb = embk + (long)tokLDS[b1 * T_ + 0] * G_;
#pragma unroll
        for (int j = 0; j < 4; ++j) { xkc[j][0] = pa[j * 64 + cb]; xkc[j][1] = pb[j * 64 + cb]; }
    }

    for (int t = 0; t < T_; ++t) {
        // A-fragments of h_{t-1}: A[m][k], m = n, k = kg*8 + jj
        const __bf16* hb = hbuf[(t + 1) & 1];
        bf16x8 a0 = *(const bf16x8*)(hb + n * S_H + kg * 8);
        bf16x8 a1 = *(const bf16x8*)(hb + n * S_H + 32 + kg * 8);

        floatx4 acc[4];
#pragma unroll
        for (int j = 0; j < 4; ++j) {
            floatx4 a = {0.f, 0.f, 0.f, 0.f};
            a = __builtin_amdgcn_mfma_f32_16x16x32_bf16(a0, bfr[j][0], a, 0, 0, 0);
            a = __builtin_amdgcn_mfma_f32_16x16x32_bf16(a1, bfr[j][1], a, 0, 0, 0);
            acc[j] = a;
        }

        // prefetch next step's xk (hidden under gate math + barrier)
        float xkn[4][2];
        if (t + 1 < T_) {
            const float* pa = embk + (long)tokLDS[b0 * T_ + t + 1] * G_;
            const float* pb = embk + (long)tokLDS[b1 * T_ + t + 1] * G_;
#pragma unroll
            for (int j = 0; j < 4; ++j) { xkn[j][0] = pa[j * 64 + cb]; xkn[j][1] = pb[j * 64 + cb]; }
        }

        // gate math: 2 live cells/lane; role selects reg pair (wave-uniform branch)
        __bf16* hw = hbuf[t & 1];
        if (role == 0) {
            cell_update_(acc[0][0] + xkc[0][0], acc[1][0] + xkc[1][0],
                         acc[2][0] + xkc[2][0], acc[3][0] + xkc[3][0],
                         c0, hw + b0 * S_H + cb);
            cell_update_(acc[0][1] + xkc[0][1], acc[1][1] + xkc[1][1],
                         acc[2][1] + xkc[2][1], acc[3][1] + xkc[3][1],
                         c1, hw + b1 * S_H + cb);
        } else {
            cell_update_(acc[0][2] + xkc[0][0], acc[1][2] + xkc[1][0],
                         acc[2][2] + xkc[2][0], acc[3][2] + xkc[3][0],
                         c0, hw + b0 * S_H + cb);
            cell_update_(acc[0][3] + xkc[0][1], acc[1][3] + xkc[1][1],
                         acc[2][3] + xkc[2][1], acc[3][3] + xkc[3][1],
                         c1, hw + b1 * S_H + cb);
        }

        if (t + 1 < T_) {
#pragma unroll
            for (int j = 0; j < 4; ++j) { xkc[j][0] = xkn[j][0]; xkc[j][1] = xkn[j][1]; }
        }

        __syncthreads();                     // h_t visible; WAR on hbuf
    }

    // out[b] = sigmoid(h_final[b] . Wd + bd); h_79 in hbuf[1]
    if (tid < 16) {
        const __bf16* hb = hbuf[1] + tid * S_H;
        float s = bd[0];
#pragma unroll
        for (int u = 0; u < U_; ++u) s = fmaf((float)hb[u], Wd[u], s);
        out[bb + tid] = sigmoidf_(s);
    }
}

// ---------------------------------------------------------------------------
extern "C" void kernel_launch(void* const* d_in, const int* in_sizes, int n_in,
                              void* d_out, int out_size, void* d_ws, size_t ws_size,
                              hipStream_t stream) {
    const int*   tokens = (const int*)  d_in[0];
    const float* emb    = (const float*)d_in[1];
    // d_in[2..4] = k0, r0, b0 : dead in the reference (cell0 state unused)
    const float* k1     = (const float*)d_in[5];
    const float* r1     = (const float*)d_in[6];
    const float* b1     = (const float*)d_in[7];
    const float* Wd     = (const float*)d_in[8];
    const float* bd     = (const float*)d_in[9];
    float*       out    = (float*)d_out;

    float* embk = (float*)d_ws;              // V_*G_ floats = 10.24 MB

    embk_kernel<<<((V_ + 63) / 64) * 2, 256, 0, stream>>>(emb, k1, b1, embk);
    lstm_kernel<<<B_ / 16, 512, 0, stream>>>(tokens, embk, r1, Wd, bd, out);
}